// Round 11
// baseline (159.228 us; speedup 1.0000x reference)
//
#include <hip/hip_runtime.h>

typedef unsigned short u16;
typedef unsigned int u32;
typedef __bf16 bf16x8 __attribute__((ext_vector_type(8)));
typedef float f32x4 __attribute__((ext_vector_type(4)));
typedef float f32x16 __attribute__((ext_vector_type(16)));
typedef u16 u16x8 __attribute__((ext_vector_type(8)));
typedef u32 u32x4 __attribute__((ext_vector_type(4)));

#define NB 64
#define NN 512
#define NH 12
#define HD 32
#define DIM 384

static constexpr size_t QWS = (size_t)NB * NH * NN * HD;  // bf16 elems per tensor
#define LOG2E 1.4426950408889634f
#define QSCALE 0.25503486f   // (1/sqrt(32)) * log2(e)

__device__ __forceinline__ u16 f2bf(float f) {
  __bf16 b = (__bf16)f;
  union { __bf16 b; u16 u; } v; v.b = b;
  return v.u;
}
__device__ __forceinline__ float lo16f(u32 w) {
  union { u32 u; float f; } v; v.u = w << 16;
  return v.f;
}
__device__ __forceinline__ float hi16f(u32 w) {
  union { u32 u; float f; } v; v.u = w & 0xffff0000u;
  return v.f;
}

// ---------------------------------------------------------------------------
// Kernel 1 (prep): blocks [0,6144): bias -> fragment-stream beR (16x16 frags,
//   for attn). blocks [6144,6360): W -> 32x32-fragment stream Wf bf16:
//   Wf[cb 36][kk 24][lane 64][8]: j = cb*32+(lane&31), k = kk*16+(lane>>5)*8+e.
// ---------------------------------------------------------------------------
__global__ __launch_bounds__(256) void prep_k(const float* __restrict__ table,
                                              const int* __restrict__ rel,
                                              const float* __restrict__ Wq,
                                              const float* __restrict__ Wkv,
                                              u32* __restrict__ beR,
                                              u16* __restrict__ Wf) {
  int bid = blockIdx.x;
  if (bid < 6144) {
    int t = bid * 256 + threadIdx.x;   // 1,572,864 words
    int word = t & 3;
    int lane = (t >> 2) & 63;
    int mf   = (t >> 8) & 3;
    int wv   = (t >> 10) & 7;
    int kt   = (t >> 13) & 15;
    int h    = t >> 17;
    int lr = lane & 15, lg = lane >> 4;
    int q = wv * 64 + mf * 16 + lr;
    int k = kt * 32 + (word >> 1) * 16 + lg * 4 + (word & 1) * 2;
    int i0 = rel[q * NN + k];
    int i1 = rel[q * NN + k + 1];
    u16 b0 = f2bf(table[i0 * NH + h] * LOG2E);
    u16 b1 = f2bf(table[i1 * NH + h] * LOG2E);
    beR[t] = (u32)b0 | ((u32)b1 << 16);
  } else {
    int t2 = (bid - 6144) * 256 + threadIdx.x;   // 0..55295 = (cb*24+kk)*64+lane
    int lane = t2 & 63;
    int kk = (t2 >> 6) % 24;
    int cb = t2 / (24 * 64);
    int j = cb * 32 + (lane & 31);
    int k = kk * 16 + (lane >> 5) * 8;
    const float* wrow = (j < 384) ? (Wq + (size_t)j * DIM) : (Wkv + (size_t)(j - 384) * DIM);
    float4 a = *(const float4*)(wrow + k);
    float4 b = *(const float4*)(wrow + k + 4);
    u16x8 o = {f2bf(a.x), f2bf(a.y), f2bf(a.z), f2bf(a.w),
               f2bf(b.x), f2bf(b.y), f2bf(b.z), f2bf(b.w)};
    *(u16x8*)(Wf + (size_t)t2 * 8) = o;
  }
}

// ---------------------------------------------------------------------------
// Kernel 2: QKV projection, fully streaming (no LDS, no barriers).
//   768 blocks x 256 thr: type = vv>>8 (q/k/v), 4 waves x 32 rows each.
//   A all-K in registers (af[24], 96 VGPR, PINNED via opaque asm so the
//   compiler cannot rematerialize). W fragments read per-MFMA directly from
//   the Wf stream (1KB coalesced dwordx4, L1/L2-hit, XCD-clustered).
//   Two split-K accumulator chains for MFMA ILP.
// ---------------------------------------------------------------------------
__global__ __launch_bounds__(256, 2) void qkv_proj_k(const float* __restrict__ x1,
                                                     const float* __restrict__ x2,
                                                     const float* __restrict__ qb,
                                                     const float* __restrict__ vb,
                                                     const u16* __restrict__ Wf,
                                                     u16* __restrict__ q_ws,
                                                     u16* __restrict__ k_ws,
                                                     u16* __restrict__ v_ws) {
  const int g = blockIdx.x;                  // 0..767
  const int vv = (g & 7) * 96 + (g >> 3);    // XCD-chunked, bijective
  const int type = vv >> 8;                  // 0:q 1:k 2:v
  const int m0 = (vv & 255) * 128;
  const int tid = threadIdx.x, lane = tid & 63, w = tid >> 6;  // w 0..3
  const int lo = lane & 31, hi = lane >> 5;
  const float* X = (type == 0) ? x1 : x2;
  const int bb = m0 >> 9, m0r = m0 & 511;
  const u16* wsrc = Wf + (size_t)type * 147456 + lane * 8;   // 12 cb * 24 kk * 512

  // A fragments: rows m0 + w*32 + lo, k = kk*16 + hi*8 + e  (af[24] = 96 VGPR)
  bf16x8 af[24];
  const float* xrow = X + (size_t)(m0 + w * 32 + lo) * DIM + hi * 8;
#pragma unroll
  for (int kk = 0; kk < 24; ++kk) {
    float4 a = *(const float4*)(xrow + kk * 16);
    float4 b = *(const float4*)(xrow + kk * 16 + 4);
    af[kk] = (bf16x8){(__bf16)a.x, (__bf16)a.y, (__bf16)a.z, (__bf16)a.w,
                      (__bf16)b.x, (__bf16)b.y, (__bf16)b.z, (__bf16)b.w};
  }
  // pin: opaque redefinition prevents rematerialization of the loads above
#pragma unroll
  for (int kk = 0; kk < 24; ++kk)
    asm volatile("" : "+v"(af[kk]));

  u16* dst = (type == 0) ? q_ws : (type == 1 ? k_ws : v_ws);
  const float scale = (type == 0) ? QSCALE : 1.0f;

  for (int c = 0; c < 12; ++c) {
    const u16* wc = wsrc + c * 12288;
    f32x16 acc0 = {};
    f32x16 acc1 = {};
#pragma unroll
    for (int kk = 0; kk < 12; ++kk) {
      bf16x8 wfa = *(const bf16x8*)(wc + kk * 512);
      bf16x8 wfb = *(const bf16x8*)(wc + (kk + 12) * 512);
      acc0 = __builtin_amdgcn_mfma_f32_32x32x16_bf16(af[kk],      wfa, acc0, 0, 0, 0);
      acc1 = __builtin_amdgcn_mfma_f32_32x32x16_bf16(af[kk + 12], wfb, acc1, 0, 0, 0);
    }
    // epilogue: colblk c == head c for this type; d = lo
    float bv = (type == 0) ? qb[c * 32 + lo] : (type == 2 ? vb[c * 32 + lo] : 0.0f);
    u16* dbase = dst + (((size_t)(bb * NH + c) * NN) + m0r + w * 32) * HD + lo;
#pragma unroll
    for (int reg = 0; reg < 16; ++reg) {
      int row = (reg & 3) + 8 * (reg >> 2) + 4 * hi;
      dbase[(size_t)row * HD] = f2bf((acc0[reg] + acc1[reg] + bv) * scale);
    }
  }
}

// ---------------------------------------------------------------------------
// Kernel 3: attention (unchanged): swapped QK + k-permuted V,
// fragment-stream bias as MFMA C operand.
// ---------------------------------------------------------------------------
__global__ __launch_bounds__(512, 4) void attn_k(const u16* __restrict__ qw,
                                                 const u16* __restrict__ kw,
                                                 const u16* __restrict__ vw,
                                                 const u32* __restrict__ beR,
                                                 float* __restrict__ out) {
  const int g = blockIdx.x;                 // 0..767
  const int vv = (g & 7) * 96 + (g >> 3);   // chunk per XCD
  const int h = vv >> 6, b = vv & 63;
  const size_t base = ((size_t)b * NH + h) * NN * HD;
  const u16* Q = qw + base;
  const u16* K = kw + base;
  const u16* V = vw + base;

  __shared__ u16 Ks[NN][40];     // [k][d], 80B stride
  __shared__ u16 Vtp[HD][520];   // [d][k-permuted], 1040B stride

  const int tid = threadIdx.x;
  const int lane = tid & 63, w = tid >> 6;
  const int lg = lane >> 4, lr = lane & 15;
  const int q0 = w * 64;

  bf16x8 qf[4];
#pragma unroll
  for (int mf = 0; mf < 4; ++mf)
    qf[mf] = *(const bf16x8*)&Q[(q0 + mf * 16 + lr) * HD + lg * 8];

  for (int c = tid; c < 2048; c += 512) {
    int row = c >> 2, part = (c & 3) * 8;
    *(u16x8*)&Ks[row][part] = *(const u16x8*)&K[row * HD + part];
    u16x8 vld = *(const u16x8*)&V[row * HD + part];
    int kk = row & 31;
    int col = (row & ~31) + ((kk >> 2) & 3) * 8 + (kk >> 4) * 4 + (kk & 3);
#pragma unroll
    for (int j = 0; j < 8; ++j) Vtp[part + j][col] = vld[j];
  }
  __syncthreads();

  const u32* bstream = beR + ((((size_t)h * 16) * 8 + w) * 4) * 256 + lane * 4;

  f32x4 accOT[4][2] = {};
  float lsum[4] = {0.f, 0.f, 0.f, 0.f};

  for (int kt = 0; kt < 16; ++kt) {
    const int k0 = kt * 32;
    const u32* bkt = bstream + (size_t)kt * 8192;
    bf16x8 kf0 = *(const bf16x8*)&Ks[k0 + lr][lg * 8];
    bf16x8 kf1 = *(const bf16x8*)&Ks[k0 + 16 + lr][lg * 8];
    bf16x8 vp0 = *(const bf16x8*)&Vtp[lr][k0 + lg * 8];
    bf16x8 vp1 = *(const bf16x8*)&Vtp[16 + lr][k0 + lg * 8];
#pragma unroll
    for (int mf = 0; mf < 4; ++mf) {
      u32x4 bbv = *(const u32x4*)(bkt + mf * 256);
      f32x4 c0 = {lo16f(bbv.x), hi16f(bbv.x), lo16f(bbv.y), hi16f(bbv.y)};
      f32x4 c1 = {lo16f(bbv.z), hi16f(bbv.z), lo16f(bbv.w), hi16f(bbv.w)};
      f32x4 s0 = __builtin_amdgcn_mfma_f32_16x16x32_bf16(kf0, qf[mf], c0, 0, 0, 0);
      f32x4 s1 = __builtin_amdgcn_mfma_f32_16x16x32_bf16(kf1, qf[mf], c1, 0, 0, 0);
      float p0[4], p1[4];
#pragma unroll
      for (int r = 0; r < 4; ++r) {
        p0[r] = __builtin_amdgcn_exp2f(s0[r]);
        p1[r] = __builtin_amdgcn_exp2f(s1[r]);
      }
      lsum[mf] += ((p0[0] + p0[1]) + (p0[2] + p0[3])) +
                  ((p1[0] + p1[1]) + (p1[2] + p1[3]));
      bf16x8 pv = {(__bf16)p0[0], (__bf16)p0[1], (__bf16)p0[2], (__bf16)p0[3],
                   (__bf16)p1[0], (__bf16)p1[1], (__bf16)p1[2], (__bf16)p1[3]};
      accOT[mf][0] = __builtin_amdgcn_mfma_f32_16x16x32_bf16(vp0, pv, accOT[mf][0], 0, 0, 0);
      accOT[mf][1] = __builtin_amdgcn_mfma_f32_16x16x32_bf16(vp1, pv, accOT[mf][1], 0, 0, 0);
    }
  }

  float linv[4];
#pragma unroll
  for (int mf = 0; mf < 4; ++mf) {
    float s = lsum[mf];
    s += __shfl_xor(s, 16, 64);
    s += __shfl_xor(s, 32, 64);
    linv[mf] = 1.0f / s;
  }

  float* outp = out + ((size_t)b * NN) * DIM + h * HD;
#pragma unroll
  for (int mf = 0; mf < 4; ++mf) {
    int q = q0 + mf * 16 + lr;
#pragma unroll
    for (int nf = 0; nf < 2; ++nf) {
      float4 o = {accOT[mf][nf][0] * linv[mf], accOT[mf][nf][1] * linv[mf],
                  accOT[mf][nf][2] * linv[mf], accOT[mf][nf][3] * linv[mf]};
      *(float4*)&outp[(size_t)q * DIM + nf * 16 + lg * 4] = o;
    }
  }
}

// ---------------------------------------------------------------------------
extern "C" void kernel_launch(void* const* d_in, const int* in_sizes, int n_in,
                              void* d_out, int out_size, void* d_ws, size_t ws_size,
                              hipStream_t stream) {
  const float* x1    = (const float*)d_in[0];
  const float* x2    = (const float*)d_in[1];
  const float* Wq    = (const float*)d_in[2];
  const float* Wkv   = (const float*)d_in[3];
  const float* qb    = (const float*)d_in[4];
  const float* vb    = (const float*)d_in[5];
  const float* table = (const float*)d_in[6];
  const int*   rel   = (const int*)d_in[7];
  float* out = (float*)d_out;

  u16* ws   = (u16*)d_ws;
  u16* q_ws = ws;
  u16* k_ws = ws + QWS;
  u16* v_ws = ws + 2 * QWS;
  u32* beR  = (u32*)(ws + 3 * QWS);          // 1,572,864 u32 = 6.3 MB
  u16* Wf   = ws + 3 * QWS + 2 * 1572864;    // 442,368 u16 = 0.88 MB

  prep_k<<<6360, 256, 0, stream>>>(table, rel, Wq, Wkv, beR, Wf);
  qkv_proj_k<<<768, 256, 0, stream>>>(x1, x2, qb, vb, Wf, q_ws, k_ws, v_ws);
  attn_k<<<NB * NH, 512, 0, stream>>>(q_ws, k_ws, v_ws, beR, out);
}

// Round 12
// 111.695 us; speedup vs baseline: 1.4256x; 1.4256x over previous
//
#include <hip/hip_runtime.h>

typedef unsigned short u16;
typedef unsigned int u32;
typedef __bf16 bf16x8 __attribute__((ext_vector_type(8)));
typedef float f32x4 __attribute__((ext_vector_type(4)));
typedef u16 u16x4 __attribute__((ext_vector_type(4)));
typedef u16 u16x8 __attribute__((ext_vector_type(8)));
typedef u32 u32x4 __attribute__((ext_vector_type(4)));

#define NB 64
#define NN 512
#define NH 12
#define HD 32
#define DIM 384

static constexpr size_t QWS = (size_t)NB * NH * NN * HD;  // bf16 elems per tensor
#define LOG2E 1.4426950408889634f
#define QSCALE 0.25503486f   // (1/sqrt(32)) * log2(e)

__device__ __forceinline__ u16 f2bf(float f) {
  __bf16 b = (__bf16)f;
  union { __bf16 b; u16 u; } v; v.b = b;
  return v.u;
}
__device__ __forceinline__ float lo16f(u32 w) {
  union { u32 u; float f; } v; v.u = w << 16;
  return v.f;
}
__device__ __forceinline__ float hi16f(u32 w) {
  union { u32 u; float f; } v; v.u = w & 0xffff0000u;
  return v.f;
}
__device__ __forceinline__ void gload16(const void* g, void* l) {
  __builtin_amdgcn_global_load_lds((const __attribute__((address_space(1))) u32*)g,
                                   (__attribute__((address_space(3))) u32*)l, 16, 0, 0);
}

// ---------------------------------------------------------------------------
// Kernel 1 (prep): blocks [0,6144): bias -> fragment-stream beR (16x16 frags).
//   blocks [6144,6360): W -> 16x16 A-frag stream Wf bf16 (R8 layout):
//   Wf[cb 72][kk 12][lane 64][8]: j = cb*16+(lane&15), k = kk*32+(lane>>4)*8+e.
// ---------------------------------------------------------------------------
__global__ __launch_bounds__(256) void prep_k(const float* __restrict__ table,
                                              const int* __restrict__ rel,
                                              const float* __restrict__ Wq,
                                              const float* __restrict__ Wkv,
                                              u32* __restrict__ beR,
                                              u16* __restrict__ Wf) {
  int bid = blockIdx.x;
  if (bid < 6144) {
    int t = bid * 256 + threadIdx.x;   // 1,572,864 words
    int word = t & 3;
    int lane = (t >> 2) & 63;
    int mf   = (t >> 8) & 3;
    int wv   = (t >> 10) & 7;
    int kt   = (t >> 13) & 15;
    int h    = t >> 17;
    int lr = lane & 15, lg = lane >> 4;
    int q = wv * 64 + mf * 16 + lr;
    int k = kt * 32 + (word >> 1) * 16 + lg * 4 + (word & 1) * 2;
    int i0 = rel[q * NN + k];
    int i1 = rel[q * NN + k + 1];
    u16 b0 = f2bf(table[i0 * NH + h] * LOG2E);
    u16 b1 = f2bf(table[i1 * NH + h] * LOG2E);
    beR[t] = (u32)b0 | ((u32)b1 << 16);
  } else {
    int t2 = (bid - 6144) * 256 + threadIdx.x;   // 0..55295 = (cb*12+kk)*64+lane
    int lane = t2 & 63;
    int kk = (t2 >> 6) % 12;
    int cb = t2 / (12 * 64);
    int j = cb * 16 + (lane & 15);
    int k = kk * 32 + (lane >> 4) * 8;
    const float* wrow = (j < 384) ? (Wq + (size_t)j * DIM) : (Wkv + (size_t)(j - 384) * DIM);
    float4 a = *(const float4*)(wrow + k);
    float4 b = *(const float4*)(wrow + k + 4);
    u16x8 o = {f2bf(a.x), f2bf(a.y), f2bf(a.z), f2bf(a.w),
               f2bf(b.x), f2bf(b.y), f2bf(b.z), f2bf(b.w)};
    *(u16x8*)(Wf + (size_t)t2 * 8) = o;
  }
}

// ---------------------------------------------------------------------------
// Kernel 2: QKV projection, swapped operands (A = W from LDS, B = X in regs).
//   768 blocks x 256 thr (4 waves x 32 rows), type = vv>>8, 12 chunks of
//   2 colblks (24KB) double-buffered via global_load_lds. Each W-frag ds_read
//   feeds 2 MFMAs (row-groups lo/hi) -> LDS traffic halved vs 16 rows/wave.
//   C layout D[j][n]: lane stores 4 consecutive d = one 8B store.
// ---------------------------------------------------------------------------
__global__ __launch_bounds__(256, 3) void qkv_proj_k(const float* __restrict__ x1,
                                                     const float* __restrict__ x2,
                                                     const float* __restrict__ qb,
                                                     const float* __restrict__ vb,
                                                     const u16* __restrict__ Wf,
                                                     u16* __restrict__ q_ws,
                                                     u16* __restrict__ k_ws,
                                                     u16* __restrict__ v_ws) {
  __shared__ __attribute__((aligned(16))) u16 Wbuf[2][12288];  // 2 x 24KB

  const int g = blockIdx.x;                  // 0..767
  const int vv = (g & 7) * 96 + (g >> 3);    // XCD-chunked, bijective
  const int type = vv >> 8;                  // 0:q 1:k 2:v
  const int m0 = (vv & 255) * 128;
  const int tid = threadIdx.x, lane = tid & 63, w = tid >> 6;  // w 0..3
  const int lg = lane >> 4, lr = lane & 15;
  const float* X = (type == 0) ? x1 : x2;
  const int bb = m0 >> 9, m0r = m0 & 511;
  const char* wsrc = (const char*)(Wf + (size_t)type * 24 * 6144);  // 24 colblks/type

  // B fragments (X): two 16-row groups, rows m0 + w*32 + {0,16} + lr, all K.
  bf16x8 aflo[12], afhi[12];
  {
    const float* xlo = X + (size_t)(m0 + w * 32 + lr) * DIM + lg * 8;
    const float* xhi = xlo + (size_t)16 * DIM;
#pragma unroll
    for (int kk = 0; kk < 12; ++kk) {
      float4 a = *(const float4*)(xlo + kk * 32);
      float4 b = *(const float4*)(xlo + kk * 32 + 4);
      aflo[kk] = (bf16x8){(__bf16)a.x, (__bf16)a.y, (__bf16)a.z, (__bf16)a.w,
                          (__bf16)b.x, (__bf16)b.y, (__bf16)b.z, (__bf16)b.w};
      float4 c = *(const float4*)(xhi + kk * 32);
      float4 d = *(const float4*)(xhi + kk * 32 + 4);
      afhi[kk] = (bf16x8){(__bf16)c.x, (__bf16)c.y, (__bf16)c.z, (__bf16)c.w,
                          (__bf16)d.x, (__bf16)d.y, (__bf16)d.z, (__bf16)d.w};
    }
  }

  // stage chunk 0: 24KB = 1536 x 16B, 256 thr -> 6 insts each
#pragma unroll
  for (int i = 0; i < 6; ++i) {
    int off = (i * 256 + tid) * 16;
    gload16(wsrc + off, (char*)&Wbuf[0][0] + off);
  }
  __syncthreads();

  u16* dst = (type == 0) ? q_ws : (type == 1 ? k_ws : v_ws);
  const float* bias = (type == 0) ? qb : (type == 2 ? vb : nullptr);
  const float scale = (type == 0) ? QSCALE : 1.0f;

  for (int c = 0; c < 12; ++c) {
    if (c + 1 < 12) {
      const char* s = wsrc + (size_t)(c + 1) * 24576;
      char* d = (char*)&Wbuf[(c + 1) & 1][0];
#pragma unroll
      for (int i = 0; i < 6; ++i) {
        int off = (i * 256 + tid) * 16;
        gload16(s + off, d + off);
      }
    }
    const u16* wb = &Wbuf[c & 1][0];
    f32x4 acc[2][2] = {};   // [lc][rowgroup]
#pragma unroll
    for (int kk = 0; kk < 12; ++kk) {
      bf16x8 wf0 = *(const bf16x8*)(wb + (kk * 64 + lane) * 8);
      bf16x8 wf1 = *(const bf16x8*)(wb + ((12 + kk) * 64 + lane) * 8);
      acc[0][0] = __builtin_amdgcn_mfma_f32_16x16x32_bf16(wf0, aflo[kk], acc[0][0], 0, 0, 0);
      acc[0][1] = __builtin_amdgcn_mfma_f32_16x16x32_bf16(wf0, afhi[kk], acc[0][1], 0, 0, 0);
      acc[1][0] = __builtin_amdgcn_mfma_f32_16x16x32_bf16(wf1, aflo[kk], acc[1][0], 0, 0, 0);
      acc[1][1] = __builtin_amdgcn_mfma_f32_16x16x32_bf16(wf1, afhi[kk], acc[1][1], 0, 0, 0);
    }
    // epilogue: colblk cb = c*2+lc (type-local). D[j][n]: lane holds
    // j = cb*16 + lg*4 + r (4 consecutive d), n = rowgroup base + lr.
#pragma unroll
    for (int lc = 0; lc < 2; ++lc) {
      int cb = c * 2 + lc;
      int head = cb >> 1;
      int d0 = (cb & 1) * 16 + lg * 4;
      float4 bv = {0.f, 0.f, 0.f, 0.f};
      if (type != 1) bv = *(const float4*)(bias + head * 32 + d0);
#pragma unroll
      for (int rg = 0; rg < 2; ++rg) {
        int n = m0r + w * 32 + rg * 16 + lr;
        u16x4 o = {f2bf((acc[lc][rg][0] + bv.x) * scale),
                   f2bf((acc[lc][rg][1] + bv.y) * scale),
                   f2bf((acc[lc][rg][2] + bv.z) * scale),
                   f2bf((acc[lc][rg][3] + bv.w) * scale)};
        *(u16x4*)(dst + ((size_t)(bb * NH + head) * NN + n) * HD + d0) = o;
      }
    }
    __syncthreads();
  }
}

// ---------------------------------------------------------------------------
// Kernel 3: attention (unchanged): swapped QK + k-permuted V,
// fragment-stream bias as MFMA C operand.
// ---------------------------------------------------------------------------
__global__ __launch_bounds__(512, 4) void attn_k(const u16* __restrict__ qw,
                                                 const u16* __restrict__ kw,
                                                 const u16* __restrict__ vw,
                                                 const u32* __restrict__ beR,
                                                 float* __restrict__ out) {
  const int g = blockIdx.x;                 // 0..767
  const int vv = (g & 7) * 96 + (g >> 3);   // chunk per XCD
  const int h = vv >> 6, b = vv & 63;
  const size_t base = ((size_t)b * NH + h) * NN * HD;
  const u16* Q = qw + base;
  const u16* K = kw + base;
  const u16* V = vw + base;

  __shared__ u16 Ks[NN][40];     // [k][d], 80B stride
  __shared__ u16 Vtp[HD][520];   // [d][k-permuted], 1040B stride

  const int tid = threadIdx.x;
  const int lane = tid & 63, w = tid >> 6;
  const int lg = lane >> 4, lr = lane & 15;
  const int q0 = w * 64;

  bf16x8 qf[4];
#pragma unroll
  for (int mf = 0; mf < 4; ++mf)
    qf[mf] = *(const bf16x8*)&Q[(q0 + mf * 16 + lr) * HD + lg * 8];

  for (int c = tid; c < 2048; c += 512) {
    int row = c >> 2, part = (c & 3) * 8;
    *(u16x8*)&Ks[row][part] = *(const u16x8*)&K[row * HD + part];
    u16x8 vld = *(const u16x8*)&V[row * HD + part];
    int kk = row & 31;
    int col = (row & ~31) + ((kk >> 2) & 3) * 8 + (kk >> 4) * 4 + (kk & 3);
#pragma unroll
    for (int j = 0; j < 8; ++j) Vtp[part + j][col] = vld[j];
  }
  __syncthreads();

  const u32* bstream = beR + ((((size_t)h * 16) * 8 + w) * 4) * 256 + lane * 4;

  f32x4 accOT[4][2] = {};
  float lsum[4] = {0.f, 0.f, 0.f, 0.f};

  for (int kt = 0; kt < 16; ++kt) {
    const int k0 = kt * 32;
    const u32* bkt = bstream + (size_t)kt * 8192;
    bf16x8 kf0 = *(const bf16x8*)&Ks[k0 + lr][lg * 8];
    bf16x8 kf1 = *(const bf16x8*)&Ks[k0 + 16 + lr][lg * 8];
    bf16x8 vp0 = *(const bf16x8*)&Vtp[lr][k0 + lg * 8];
    bf16x8 vp1 = *(const bf16x8*)&Vtp[16 + lr][k0 + lg * 8];
#pragma unroll
    for (int mf = 0; mf < 4; ++mf) {
      u32x4 bbv = *(const u32x4*)(bkt + mf * 256);
      f32x4 c0 = {lo16f(bbv.x), hi16f(bbv.x), lo16f(bbv.y), hi16f(bbv.y)};
      f32x4 c1 = {lo16f(bbv.z), hi16f(bbv.z), lo16f(bbv.w), hi16f(bbv.w)};
      f32x4 s0 = __builtin_amdgcn_mfma_f32_16x16x32_bf16(kf0, qf[mf], c0, 0, 0, 0);
      f32x4 s1 = __builtin_amdgcn_mfma_f32_16x16x32_bf16(kf1, qf[mf], c1, 0, 0, 0);
      float p0[4], p1[4];
#pragma unroll
      for (int r = 0; r < 4; ++r) {
        p0[r] = __builtin_amdgcn_exp2f(s0[r]);
        p1[r] = __builtin_amdgcn_exp2f(s1[r]);
      }
      lsum[mf] += ((p0[0] + p0[1]) + (p0[2] + p0[3])) +
                  ((p1[0] + p1[1]) + (p1[2] + p1[3]));
      bf16x8 pv = {(__bf16)p0[0], (__bf16)p0[1], (__bf16)p0[2], (__bf16)p0[3],
                   (__bf16)p1[0], (__bf16)p1[1], (__bf16)p1[2], (__bf16)p1[3]};
      accOT[mf][0] = __builtin_amdgcn_mfma_f32_16x16x32_bf16(vp0, pv, accOT[mf][0], 0, 0, 0);
      accOT[mf][1] = __builtin_amdgcn_mfma_f32_16x16x32_bf16(vp1, pv, accOT[mf][1], 0, 0, 0);
    }
  }

  float linv[4];
#pragma unroll
  for (int mf = 0; mf < 4; ++mf) {
    float s = lsum[mf];
    s += __shfl_xor(s, 16, 64);
    s += __shfl_xor(s, 32, 64);
    linv[mf] = 1.0f / s;
  }

  float* outp = out + ((size_t)b * NN) * DIM + h * HD;
#pragma unroll
  for (int mf = 0; mf < 4; ++mf) {
    int q = q0 + mf * 16 + lr;
#pragma unroll
    for (int nf = 0; nf < 2; ++nf) {
      float4 o = {accOT[mf][nf][0] * linv[mf], accOT[mf][nf][1] * linv[mf],
                  accOT[mf][nf][2] * linv[mf], accOT[mf][nf][3] * linv[mf]};
      *(float4*)&outp[(size_t)q * DIM + nf * 16 + lg * 4] = o;
    }
  }
}

// ---------------------------------------------------------------------------
extern "C" void kernel_launch(void* const* d_in, const int* in_sizes, int n_in,
                              void* d_out, int out_size, void* d_ws, size_t ws_size,
                              hipStream_t stream) {
  const float* x1    = (const float*)d_in[0];
  const float* x2    = (const float*)d_in[1];
  const float* Wq    = (const float*)d_in[2];
  const float* Wkv   = (const float*)d_in[3];
  const float* qb    = (const float*)d_in[4];
  const float* vb    = (const float*)d_in[5];
  const float* table = (const float*)d_in[6];
  const int*   rel   = (const int*)d_in[7];
  float* out = (float*)d_out;

  u16* ws   = (u16*)d_ws;
  u16* q_ws = ws;
  u16* k_ws = ws + QWS;
  u16* v_ws = ws + 2 * QWS;
  u32* beR  = (u32*)(ws + 3 * QWS);          // 1,572,864 u32 = 6.3 MB
  u16* Wf   = ws + 3 * QWS + 2 * 1572864;    // 442,368 u16 = 0.88 MB

  prep_k<<<6360, 256, 0, stream>>>(table, rel, Wq, Wkv, beR, Wf);
  qkv_proj_k<<<768, 256, 0, stream>>>(x1, x2, qb, vb, Wf, q_ws, k_ws, v_ws);
  attn_k<<<NB * NH, 512, 0, stream>>>(q_ws, k_ws, v_ws, beR, out);
}